// Round 1
// baseline (2678.605 us; speedup 1.0000x reference)
//
#include <hip/hip_runtime.h>
#include <math.h>

#define TSEQ 1024
#define NH   16
#define DH   64
#define CDIM 1024
#define BATCH 4

// ---------------- f32 tiled GEMM: C[M,N] = A[M,K] @ B[K,N], row-major ----------------
// BM=BN=64, BK=16, 256 threads, 4x4 microtile per thread. All dims divide tiles.
template<int BM, int BN, int BK>
__global__ __launch_bounds__(256) void gemm_f32(const float* __restrict__ A,
                                                const float* __restrict__ B,
                                                float* __restrict__ C,
                                                int M, int N, int K) {
    __shared__ float As[BM][BK + 1];   // +1 pad: avoid bank conflicts on write
    __shared__ float Bs[BK][BN];
    const int tid = threadIdx.x;
    const int tx = tid & 15;    // col group 0..15
    const int ty = tid >> 4;    // row group 0..15
    const int row0 = blockIdx.y * BM;
    const int col0 = blockIdx.x * BN;

    float acc[4][4] = {};
    for (int k0 = 0; k0 < K; k0 += BK) {
        // A tile: 64x16, 4 elems/thread, coalesced over k
        {
            const int col = tid & 15;
            const int rbase = tid >> 4;
            #pragma unroll
            for (int i = 0; i < 4; ++i) {
                int r = rbase + 16 * i;
                As[r][col] = A[(size_t)(row0 + r) * K + k0 + col];
            }
        }
        // B tile: 16x64, 4 elems/thread, coalesced over n
        {
            const int col = tid & 63;
            const int rbase = tid >> 6;
            #pragma unroll
            for (int i = 0; i < 4; ++i) {
                int r = rbase + 4 * i;
                Bs[r][col] = B[(size_t)(k0 + r) * N + col0 + col];
            }
        }
        __syncthreads();
        #pragma unroll
        for (int kk = 0; kk < BK; ++kk) {
            float a[4], b[4];
            #pragma unroll
            for (int i = 0; i < 4; ++i) a[i] = As[ty + 16 * i][kk];
            #pragma unroll
            for (int j = 0; j < 4; ++j) b[j] = Bs[kk][tx + 16 * j];
            #pragma unroll
            for (int i = 0; i < 4; ++i)
                #pragma unroll
                for (int j = 0; j < 4; ++j)
                    acc[i][j] += a[i] * b[j];
        }
        __syncthreads();
    }
    #pragma unroll
    for (int i = 0; i < 4; ++i) {
        int r = row0 + ty + 16 * i;
        #pragma unroll
        for (int j = 0; j < 4; ++j)
            C[(size_t)r * N + col0 + tx + 16 * j] = acc[i][j];
    }
}

// ---------------- fused causal attention with relative position embeddings ----------
// logit[t,s] = q_t . (scale*k_s + embk[t-s]);  y_t = sum_s softmax(logit)_s * (v_s + embv[t-s])
// grid: (T/4, B*H); block 256 = 4 waves; wave w owns query row t = 4*blockIdx.x + w.
// lane = dim for q/acc;  lane = s_local for logits (phase A).
__global__ __launch_bounds__(256) void attn_rpe(const float* __restrict__ qkv,
                                                const float* __restrict__ embk,
                                                const float* __restrict__ embv,
                                                float* __restrict__ y) {
    __shared__ float Ks[64][65];    // scale*k, padded -> 2-way (free) on column gathers
    __shared__ float Vs[64][64];
    __shared__ float EK[67][65];    // embk rows for delta in [t0-s0-63, t0-s0+3]
    __shared__ float Plds[4][64];   // per-wave softmax probs

    const int tid  = threadIdx.x;
    const int w    = tid >> 6;
    const int lane = tid & 63;
    const int t0   = blockIdx.x * 4;
    const int t    = t0 + w;
    const int bh   = blockIdx.y;
    const int b    = bh >> 4;   // / NH
    const int h    = bh & 15;

    const float scale = 0.125f;             // 1/sqrt(64)
    const size_t rowstride = 3 * CDIM;

    const float qval = qkv[((size_t)(b * TSEQ + t)) * rowstride + h * DH + lane];

    float m = -INFINITY, ll = 0.f, acc = 0.f;

    const int nchunks = t0 / 64 + 1;
    for (int c = 0; c < nchunks; ++c) {
        const int s0 = c * 64;
        __syncthreads();   // previous chunk's phase A/B reads done before overwrite
        // stage K (pre-scaled) and V
        for (int idx = tid; idx < 64 * 64; idx += 256) {
            int sr = idx >> 6, col = idx & 63;
            size_t base = ((size_t)(b * TSEQ + s0 + sr)) * rowstride + h * DH + col;
            Ks[sr][col] = qkv[base + CDIM] * scale;
            Vs[sr][col] = qkv[base + 2 * CDIM];
        }
        // stage embk rows; clamp out-of-range deltas (masked lanes never use them)
        for (int idx = tid; idx < 67 * 64; idx += 256) {
            int r = idx >> 6, col = idx & 63;
            if (r < 67) {
                int delta = t0 - s0 - 63 + r;
                int dc = delta < 0 ? 0 : (delta > TSEQ - 1 ? TSEQ - 1 : delta);
                EK[r][col] = embk[dc * DH + col];
            }
        }
        __syncthreads();

        // ---- phase A: lane = s_local, compute 64 logits for row t ----
        float logit = 0.f;
        const int erow = 63 + w - lane;    // EK row index for delta = t - (s0+lane)
        #pragma unroll
        for (int j = 0; j < 64; ++j) {
            float qj = __shfl(qval, j);
            logit += qj * (Ks[lane][j] + EK[erow][j]);
        }
        const int s = s0 + lane;
        if (s > t) logit = -INFINITY;

        // online softmax
        float mc = logit;
        #pragma unroll
        for (int off = 32; off > 0; off >>= 1)
            mc = fmaxf(mc, __shfl_xor(mc, off));
        const float m_new = fmaxf(m, mc);
        const float p = __expf(logit - m_new);     // masked lanes -> 0
        const float alpha = __expf(m - m_new);     // first chunk: 0
        float ps = p;
        #pragma unroll
        for (int off = 32; off > 0; off >>= 1)
            ps += __shfl_xor(ps, off);
        ll = ll * alpha + ps;
        acc *= alpha;
        m = m_new;
        Plds[w][lane] = p;

        // ---- phase B: lane = dim, accumulate y ----
        #pragma unroll
        for (int sl = 0; sl < 64; ++sl) {
            float pv = Plds[w][sl];               // LDS broadcast
            int delta = t - s0 - sl;
            int dc = delta < 0 ? 0 : delta;       // pv==0 when delta<0
            acc += pv * (Vs[sl][lane] + embv[dc * DH + lane]);  // coalesced embv read
        }
    }
    y[((size_t)(b * TSEQ + t)) * CDIM + h * DH + lane] = acc / ll;
}

extern "C" void kernel_launch(void* const* d_in, const int* in_sizes, int n_in,
                              void* d_out, int out_size, void* d_ws, size_t ws_size,
                              hipStream_t stream) {
    const float* x      = (const float*)d_in[0];   // [4,1024,1024]
    const float* w_attn = (const float*)d_in[1];   // [1024,3072]
    const float* w_proj = (const float*)d_in[2];   // [1024,1024]
    const float* embk   = (const float*)d_in[3];   // [1024,64]
    const float* embv   = (const float*)d_in[4];   // [1024,64]
    float* out = (float*)d_out;                    // [4,1024,1024]

    float* qkv  = (float*)d_ws;                    // 4096*3072 f32 = 50.3 MB
    float* ymid = qkv + (size_t)4096 * 3072;       // 4096*1024 f32 = 16.8 MB

    dim3 blk(256);
    gemm_f32<64, 64, 16><<<dim3(3072 / 64, 4096 / 64), blk, 0, stream>>>(
        x, w_attn, qkv, 4096, 3072, 1024);
    attn_rpe<<<dim3(TSEQ / 4, BATCH * NH), blk, 0, stream>>>(qkv, embk, embv, ymid);
    gemm_f32<64, 64, 16><<<dim3(1024 / 64, 4096 / 64), blk, 0, stream>>>(
        ymid, w_proj, out, 4096, 1024, 1024);
}

// Round 2
// 1129.113 us; speedup vs baseline: 2.3723x; 2.3723x over previous
//
#include <hip/hip_runtime.h>
#include <math.h>

typedef unsigned short u16;
typedef short bf8 __attribute__((ext_vector_type(8)));      // 8 bf16 (raw bits)
typedef float f32x4 __attribute__((ext_vector_type(4)));

__device__ __forceinline__ u16 f2b(float f) {
    union { float f; unsigned u; } x; x.f = f;
    return (u16)((x.u + 0x7FFFu + ((x.u >> 16) & 1u)) >> 16);   // RTNE
}
__device__ __forceinline__ float b2f(u16 b) {
    union { unsigned u; float f; } x; x.u = ((unsigned)b) << 16;
    return x.f;
}
__device__ __forceinline__ bf8 pack8(const float* p) {
    bf8 r;
    #pragma unroll
    for (int i = 0; i < 8; ++i) r[i] = (short)f2b(p[i]);
    return r;
}

// wave-local LDS fence: make cross-lane ds_writes visible to subsequent ds_reads
#define LDS_FENCE() do { __builtin_amdgcn_wave_barrier(); \
                         __builtin_amdgcn_s_waitcnt(0xC07F); /* lgkmcnt(0) */ \
                         __builtin_amdgcn_wave_barrier(); } while (0)

// ---------------- f32 tiled GEMM (unchanged from R0, correct) ----------------
template<int BM, int BN, int BK>
__global__ __launch_bounds__(256) void gemm_f32(const float* __restrict__ A,
                                                const float* __restrict__ B,
                                                float* __restrict__ C,
                                                int M, int N, int K) {
    __shared__ float As[BM][BK + 1];
    __shared__ float Bs[BK][BN];
    const int tid = threadIdx.x;
    const int tx = tid & 15, ty = tid >> 4;
    const int row0 = blockIdx.y * BM, col0 = blockIdx.x * BN;
    float acc[4][4] = {};
    for (int k0 = 0; k0 < K; k0 += BK) {
        {
            const int col = tid & 15, rbase = tid >> 4;
            #pragma unroll
            for (int i = 0; i < 4; ++i) {
                int r = rbase + 16 * i;
                As[r][col] = A[(size_t)(row0 + r) * K + k0 + col];
            }
        }
        {
            const int col = tid & 63, rbase = tid >> 6;
            #pragma unroll
            for (int i = 0; i < 4; ++i) {
                int r = rbase + 4 * i;
                Bs[r][col] = B[(size_t)(k0 + r) * N + col0 + col];
            }
        }
        __syncthreads();
        #pragma unroll
        for (int kk = 0; kk < BK; ++kk) {
            float a[4], b[4];
            #pragma unroll
            for (int i = 0; i < 4; ++i) a[i] = As[ty + 16 * i][kk];
            #pragma unroll
            for (int j = 0; j < 4; ++j) b[j] = Bs[kk][tx + 16 * j];
            #pragma unroll
            for (int i = 0; i < 4; ++i)
                #pragma unroll
                for (int j = 0; j < 4; ++j)
                    acc[i][j] += a[i] * b[j];
        }
        __syncthreads();
    }
    #pragma unroll
    for (int i = 0; i < 4; ++i) {
        int r = row0 + ty + 16 * i;
        #pragma unroll
        for (int j = 0; j < 4; ++j)
            C[(size_t)r * N + col0 + tx + 16 * j] = acc[i][j];
    }
}

// ---------------- prep: bf16 copies of K (pre-scaled), embk / embv^T tables ----------
// Kb  [64bh*1024 s][64 d]   = 0.125 * K
// EKT [1152][64]            row r = embk[clamp(r-64)]          (row 64+delta)
// EVT [64][1152]            col c = embv[clamp(c-63)][d]       (col 63+delta)
__global__ __launch_bounds__(256) void prep_bf16(const float* __restrict__ qkv,
                                                 const float* __restrict__ embk,
                                                 const float* __restrict__ embv,
                                                 u16* __restrict__ Kb,
                                                 u16* __restrict__ EKT,
                                                 u16* __restrict__ EVT) {
    int idx = blockIdx.x * 256 + threadIdx.x;
    if (idx < 1048576) {
        int d4 = (idx & 15) * 4;
        int srow = idx >> 4;                 // bh*1024 + s
        int bh = srow >> 10, s = srow & 1023;
        int b = bh >> 4, h = bh & 15;
        const float* p = qkv + (size_t)(b * 1024 + s) * 3072 + 1024 + h * 64 + d4;
        u16* o = Kb + ((size_t)srow << 6) + d4;
        #pragma unroll
        for (int i = 0; i < 4; ++i) o[i] = f2b(p[i] * 0.125f);
    } else if (idx < 1048576 + 18432) {
        int t = idx - 1048576;
        int row = t >> 4, d4 = (t & 15) * 4;
        int delta = row - 64;
        int cl = delta < 0 ? 0 : (delta > 1023 ? 1023 : delta);
        const float* p = embk + cl * 64 + d4;
        u16* o = EKT + row * 64 + d4;
        #pragma unroll
        for (int i = 0; i < 4; ++i) o[i] = f2b(p[i]);
    } else if (idx < 1048576 + 36864) {
        int t = idx - 1048576 - 18432;
        int d = t / 288, c4 = (t - d * 288) * 4;
        u16* o = EVT + d * 1152 + c4;
        #pragma unroll
        for (int i = 0; i < 4; ++i) {
            int delta = c4 + i - 63;
            int cl = delta < 0 ? 0 : (delta > 1023 ? 1023 : delta);
            o[i] = f2b(embv[cl * 64 + d]);
        }
    }
}

// ---------------- prep: V^T bf16   Vt[64bh*64 + d][1024 s] ----------------
__global__ __launch_bounds__(256) void prep_vt(const float* __restrict__ qkv,
                                               u16* __restrict__ Vt) {
    __shared__ float ts[64][65];
    const int tid = threadIdx.x;
    const int s0 = blockIdx.x * 64;
    const int bh = blockIdx.y, b = bh >> 4, h = bh & 15;
    #pragma unroll
    for (int it = 0; it < 4; ++it) {
        int s = it * 16 + (tid >> 4);
        int d4 = (tid & 15) * 4;
        const float* p = qkv + (size_t)(b * 1024 + s0 + s) * 3072 + 2048 + h * 64 + d4;
        #pragma unroll
        for (int i = 0; i < 4; ++i) ts[s][d4 + i] = p[i];
    }
    __syncthreads();
    const int d = tid >> 2, si = (tid & 3) * 16;
    __align__(16) u16 buf[16];
    #pragma unroll
    for (int i = 0; i < 16; ++i) buf[i] = f2b(ts[si + i][d]);
    u16* o = Vt + ((size_t)(bh * 64 + d) << 10) + s0 + si;
    *(uint4*)o       = ((uint4*)buf)[0];
    *(uint4*)(o + 8) = ((uint4*)buf)[1];
}

// ---------------- MFMA fused attention with RPE (flash-style, barrier-free) --------
// grid (16 qtiles, 64 bh), 256 thr = 4 waves; wave w owns 16 query rows.
__global__ __launch_bounds__(256) void attn_mfma(const float* __restrict__ qkv,
                                                 const u16* __restrict__ Kb,
                                                 const u16* __restrict__ Vt,
                                                 const u16* __restrict__ EKT,
                                                 const u16* __restrict__ EVT,
                                                 float* __restrict__ y) {
    __shared__ __align__(16) u16 S2l[4][16 * 80];   // per-wave S2 slab (delta window)
    __shared__ __align__(16) u16 Pl [4][2 * 512];   // per-wave P, MFMA A-layout
    __shared__ __align__(16) u16 Ppl[4][3 * 512];   // per-wave sheared P'

    const int tid = threadIdx.x;
    const int w = tid >> 6, L = tid & 63;
    const int l15 = L & 15, quad = L >> 4;
    const int tile = (int)gridDim.x - 1 - (int)blockIdx.x;   // heavy tiles first
    const int t0 = tile * 64;
    const int bh = blockIdx.y, b = bh >> 4, h = bh & 15;
    const int W0 = (w >> 1) * 32;                   // 32-aligned P' delta window base

    bf8 qf[2];
    {
        const int trow = t0 + w * 16 + l15;         // A-frag: m = lane&15
        const float* qp = qkv + (size_t)(b * 1024 + trow) * 3072 + h * 64 + quad * 8;
        qf[0] = pack8(qp);
        qf[1] = pack8(qp + 32);
    }

    f32x4 o[4] = {};
    float mrow[4] = {-1e30f, -1e30f, -1e30f, -1e30f};
    float lrow[4] = {0.f, 0.f, 0.f, 0.f};

    const int nch = (t0 >> 6) + 1;
    for (int c = 0; c < nch; ++c) {
        const int s0 = c << 6;
        const int diff = t0 - s0;

        // ---- S1 = Qb @ (0.125*K)^T ----
        f32x4 s1[4] = {};
        {
            const u16* kbase = Kb + ((size_t)(bh * 1024 + s0) << 6) + quad * 8;
            #pragma unroll
            for (int tn = 0; tn < 4; ++tn) {
                const u16* kp = kbase + ((size_t)(tn * 16 + l15) << 6);
                #pragma unroll
                for (int kc = 0; kc < 2; ++kc)
                    s1[tn] = __builtin_amdgcn_mfma_f32_16x16x32_bf16(
                        qf[kc], *(const bf8*)(kp + kc * 32), s1[tn], 0, 0, 0);
            }
        }
        // ---- S2 = Q @ EK^T over wave delta-window [w*16, w*16+80) ----
        f32x4 s2[5] = {};
        {
            // EKT row = 64 + (diff-63) + w*16 + jtile*16 + lane15
            const u16* ekbase = EKT + ((size_t)(1 + diff + w * 16 + l15) << 6) + quad * 8;
            #pragma unroll
            for (int j = 0; j < 5; ++j) {
                const u16* ep = ekbase + ((size_t)(j * 16) << 6);
                #pragma unroll
                for (int kc = 0; kc < 2; ++kc)
                    s2[j] = __builtin_amdgcn_mfma_f32_16x16x32_bf16(
                        qf[kc], *(const bf8*)(ep + kc * 32), s2[j], 0, 0, 0);
            }
        }
        // stash S2 (bf16) for the shear gather; zero P'
        #pragma unroll
        for (int j = 0; j < 5; ++j)
            #pragma unroll
            for (int r = 0; r < 4; ++r)
                S2l[w][(quad * 4 + r) * 80 + j * 16 + l15] = f2b(s2[j][r]);
        #pragma unroll
        for (int i = 0; i < 3; ++i)
            ((uint4*)Ppl[w])[i * 64 + L] = make_uint4(0, 0, 0, 0);
        LDS_FENCE();

        // ---- logits + online softmax in C-layout (row = quad*4+r, col = tn*16+l15) ----
        #pragma unroll
        for (int tn = 0; tn < 4; ++tn) {
            const int cl = tn * 16 + l15;
            #pragma unroll
            for (int r = 0; r < 4; ++r) {
                const int row = quad * 4 + r;
                float v = s1[tn][r] + b2f(S2l[w][row * 80 + (row - cl + 63)]);
                if (cl > diff + w * 16 + row) v = -1e30f;   // causal (only diag chunk)
                s1[tn][r] = v;
            }
        }
        #pragma unroll
        for (int r = 0; r < 4; ++r) {
            float mx = fmaxf(fmaxf(s1[0][r], s1[1][r]), fmaxf(s1[2][r], s1[3][r]));
            mx = fmaxf(mx, __shfl_xor(mx, 1));
            mx = fmaxf(mx, __shfl_xor(mx, 2));
            mx = fmaxf(mx, __shfl_xor(mx, 4));
            mx = fmaxf(mx, __shfl_xor(mx, 8));
            const float mnew = fmaxf(mrow[r], mx);
            const float alpha = __expf(mrow[r] - mnew);
            mrow[r] = mnew;
            float rs = 0.f;
            #pragma unroll
            for (int tn = 0; tn < 4; ++tn) {
                float p = __expf(s1[tn][r] - mnew);
                s1[tn][r] = p;
                rs += p;
            }
            rs += __shfl_xor(rs, 1); rs += __shfl_xor(rs, 2);
            rs += __shfl_xor(rs, 4); rs += __shfl_xor(rs, 8);
            lrow[r] = lrow[r] * alpha + rs;
            #pragma unroll
            for (int tn = 0; tn < 4; ++tn) o[tn][r] *= alpha;
        }
        // ---- write P and sheared P' in MFMA A-layout ----
        #pragma unroll
        for (int tn = 0; tn < 4; ++tn) {
            const int cl = tn * 16 + l15;
            #pragma unroll
            for (int r = 0; r < 4; ++r) {
                const int row = quad * 4 + r;
                const u16 pb = f2b(s1[tn][r]);
                Pl[w][((cl >> 5) << 9) + (((cl >> 3) & 3) << 7) + (row << 3) + (cl & 7)] = pb;
                const int dc = (w & 1) * 16 + row - cl + 63;   // in [0,94]
                Ppl[w][((dc >> 5) << 9) + (((dc >> 3) & 3) << 7) + (row << 3) + (dc & 7)] = pb;
            }
        }
        LDS_FENCE();

        // ---- O += P @ V   (B-frags direct from Vt global) ----
        {
            bf8 pa[2];
            #pragma unroll
            for (int kc = 0; kc < 2; ++kc) pa[kc] = ((const bf8*)Pl[w])[kc * 64 + L];
            const u16* vbase = Vt + ((size_t)(bh * 64 + l15) << 10) + s0 + quad * 8;
            #pragma unroll
            for (int tn = 0; tn < 4; ++tn) {
                const u16* vp = vbase + ((size_t)(tn * 16) << 10);
                #pragma unroll
                for (int kc = 0; kc < 2; ++kc)
                    o[tn] = __builtin_amdgcn_mfma_f32_16x16x32_bf16(
                        pa[kc], *(const bf8*)(vp + kc * 32), o[tn], 0, 0, 0);
            }
        }
        // ---- O += P' @ EV  (cols 63+delta; base ≡ 0 mod 8 → aligned 16B loads) ----
        {
            bf8 pa[3];
            #pragma unroll
            for (int kc = 0; kc < 3; ++kc) pa[kc] = ((const bf8*)Ppl[w])[kc * 64 + L];
            const u16* evbase = EVT + (size_t)l15 * 1152 + diff + W0 + quad * 8;
            #pragma unroll
            for (int tn = 0; tn < 4; ++tn) {
                const u16* evp = evbase + (size_t)(tn * 16) * 1152;
                #pragma unroll
                for (int kc = 0; kc < 3; ++kc)
                    o[tn] = __builtin_amdgcn_mfma_f32_16x16x32_bf16(
                        pa[kc], *(const bf8*)(evp + kc * 32), o[tn], 0, 0, 0);
            }
        }
        LDS_FENCE();   // scratch reuse next chunk
    }
    // epilogue: O / l  (C-layout)
    #pragma unroll
    for (int tn = 0; tn < 4; ++tn) {
        const int col = h * 64 + tn * 16 + l15;
        #pragma unroll
        for (int r = 0; r < 4; ++r) {
            const int trow = t0 + w * 16 + quad * 4 + r;
            y[(size_t)(b * 1024 + trow) * 1024 + col] = o[tn][r] / lrow[r];
        }
    }
}

extern "C" void kernel_launch(void* const* d_in, const int* in_sizes, int n_in,
                              void* d_out, int out_size, void* d_ws, size_t ws_size,
                              hipStream_t stream) {
    const float* x      = (const float*)d_in[0];
    const float* w_attn = (const float*)d_in[1];
    const float* w_proj = (const float*)d_in[2];
    const float* embk   = (const float*)d_in[3];
    const float* embv   = (const float*)d_in[4];
    float* out = (float*)d_out;

    float* qkv  = (float*)d_ws;                    // 12.58M f32
    float* ymid = qkv + 12582912;                  // 4.19M f32
    u16*   Kb   = (u16*)(ymid + 4194304);          // 4.19M u16
    u16*   Vt   = Kb + 4194304;                    // 4.19M u16
    u16*   EKT  = Vt + 4194304;                    // 73728 u16
    u16*   EVT  = EKT + 73728;                     // 73728 u16

    gemm_f32<64, 64, 16><<<dim3(48, 64), 256, 0, stream>>>(x, w_attn, qkv, 4096, 3072, 1024);
    prep_bf16<<<dim3(4240), 256, 0, stream>>>(qkv, embk, embv, Kb, EKT, EVT);
    prep_vt<<<dim3(16, 64), 256, 0, stream>>>(qkv, Vt);
    attn_mfma<<<dim3(16, 64), 256, 0, stream>>>(qkv, Kb, Vt, EKT, EVT, ymid);
    gemm_f32<64, 64, 16><<<dim3(16, 64), 256, 0, stream>>>(ymid, w_proj, out, 4096, 1024, 1024);
}

// Round 3
// 589.665 us; speedup vs baseline: 4.5426x; 1.9148x over previous
//
#include <hip/hip_runtime.h>
#include <math.h>

typedef unsigned short u16;
typedef short bf8 __attribute__((ext_vector_type(8)));      // 8 bf16 (raw bits)
typedef float f32x4 __attribute__((ext_vector_type(4)));

__device__ __forceinline__ u16 f2b(float f) {
    union { float f; unsigned u; } x; x.f = f;
    return (u16)((x.u + 0x7FFFu + ((x.u >> 16) & 1u)) >> 16);   // RTNE
}
__device__ __forceinline__ float b2f(u16 b) {
    union { unsigned u; float f; } x; x.u = ((unsigned)b) << 16;
    return x.f;
}

__device__ __forceinline__ void async16(const void* g, void* l) {
    __builtin_amdgcn_global_load_lds(
        (const __attribute__((address_space(1))) unsigned int*)g,
        (__attribute__((address_space(3))) unsigned int*)l, 16, 0, 0);
}

__device__ __forceinline__ void cstore(float* p, float v) { *p = v; }
__device__ __forceinline__ void cstore(u16* p, float v) { *p = f2b(v); }

// wave-local LDS fence
#define LDS_FENCE() do { __builtin_amdgcn_wave_barrier(); \
                         __builtin_amdgcn_s_waitcnt(0xC07F); /* lgkmcnt(0) */ \
                         __builtin_amdgcn_wave_barrier(); } while (0)

// ---------------- bf16 MFMA GEMM (m97 structure): C[M,N] = A[M,K] @ Bt[N,K]^T ------
// 128x128 tile, BK=32, 256 thr = 4 waves, each wave 64x64 (4x4 MFMA 16x16x32).
template<typename OutT>
__global__ __launch_bounds__(256) void gemm_mfma(const u16* __restrict__ A,
                                                 const u16* __restrict__ Bt,
                                                 OutT* __restrict__ C,
                                                 int M, int N, int K) {
    __shared__ __align__(16) u16 As[128 * 32];
    __shared__ __align__(16) u16 Bs[128 * 32];
    const int tid = threadIdx.x;
    const int w = tid >> 6, L = tid & 63;
    const int l15 = L & 15, quad = L >> 4;
    const int wm = (w >> 1) * 64, wn = (w & 1) * 64;
    const int row0 = blockIdx.y * 128, col0 = blockIdx.x * 128;
    const int laneRow = L >> 2, laneCol8 = (L & 3) * 8;

    f32x4 acc[4][4] = {};

    for (int k0 = 0; k0 < K; k0 += 32) {
        #pragma unroll
        for (int i = 0; i < 2; ++i) {
            const int seg = w * 2 + i;
            const int r = seg * 16 + laneRow;
            async16(&A[(size_t)(row0 + r) * K + k0 + laneCol8], &As[seg * 512 + L * 8]);
        }
        #pragma unroll
        for (int i = 0; i < 2; ++i) {
            const int seg = w * 2 + i;
            const int r = seg * 16 + laneRow;
            async16(&Bt[(size_t)(col0 + r) * K + k0 + laneCol8], &Bs[seg * 512 + L * 8]);
        }
        __syncthreads();
        bf8 a[4], b[4];
        #pragma unroll
        for (int mt = 0; mt < 4; ++mt)
            a[mt] = *(const bf8*)&As[(wm + mt * 16 + l15) * 32 + quad * 8];
        #pragma unroll
        for (int nt = 0; nt < 4; ++nt)
            b[nt] = *(const bf8*)&Bs[(wn + nt * 16 + l15) * 32 + quad * 8];
        #pragma unroll
        for (int mt = 0; mt < 4; ++mt)
            #pragma unroll
            for (int nt = 0; nt < 4; ++nt)
                acc[mt][nt] = __builtin_amdgcn_mfma_f32_16x16x32_bf16(
                    a[mt], b[nt], acc[mt][nt], 0, 0, 0);
        __syncthreads();
    }
    #pragma unroll
    for (int mt = 0; mt < 4; ++mt)
        #pragma unroll
        for (int nt = 0; nt < 4; ++nt) {
            const int col = col0 + wn + nt * 16 + l15;
            #pragma unroll
            for (int r = 0; r < 4; ++r) {
                const int row = row0 + wm + mt * 16 + quad * 4 + r;
                cstore(&C[(size_t)row * N + col], acc[mt][nt][r]);
            }
        }
}

// ---------------- prep: x -> bf16; EKT/EVT clamped tables (bf16) ----------------
// EKT [1152][64]  row r = embk[clamp(r-64)]     EVT [64][1152] col c = embv[clamp(c-63)][d]
__global__ __launch_bounds__(256) void prep_conv(const float* __restrict__ x,
                                                 const float* __restrict__ embk,
                                                 const float* __restrict__ embv,
                                                 u16* __restrict__ xb,
                                                 u16* __restrict__ EKT,
                                                 u16* __restrict__ EVT) {
    int idx = blockIdx.x * 256 + threadIdx.x;
    if (idx < 1048576) {
        const float4 v = ((const float4*)x)[idx];
        ((ushort4*)xb)[idx] = make_ushort4(f2b(v.x), f2b(v.y), f2b(v.z), f2b(v.w));
    } else if (idx < 1048576 + 18432) {
        int t = idx - 1048576;
        int row = t >> 4, d4 = (t & 15) * 4;
        int delta = row - 64;
        int cl = delta < 0 ? 0 : (delta > 1023 ? 1023 : delta);
        const float* p = embk + cl * 64 + d4;
        u16* o = EKT + row * 64 + d4;
        #pragma unroll
        for (int i = 0; i < 4; ++i) o[i] = f2b(p[i]);
    } else if (idx < 1048576 + 36864) {
        int t = idx - 1048576 - 18432;
        int d = t / 288, c4 = (t - d * 288) * 4;
        u16* o = EVT + d * 1152 + c4;
        #pragma unroll
        for (int i = 0; i < 4; ++i) {
            int delta = c4 + i - 63;
            int cl = delta < 0 ? 0 : (delta > 1023 ? 1023 : delta);
            o[i] = f2b(embv[cl * 64 + d]);
        }
    }
}

// ---------------- prep: W[R][C] f32 -> WT[C][R] bf16 ----------------
__global__ __launch_bounds__(256) void transpose_conv(const float* __restrict__ W,
                                                      u16* __restrict__ WT,
                                                      int R, int Cc) {
    __shared__ u16 t[64][65];
    const int tid = threadIdx.x;
    const int c0 = blockIdx.x * 64, r0 = blockIdx.y * 64;
    for (int i = tid; i < 4096; i += 256) {
        int r = i >> 6, c = i & 63;
        t[r][c] = f2b(W[(size_t)(r0 + r) * Cc + c0 + c]);
    }
    __syncthreads();
    for (int i = tid; i < 4096; i += 256) {
        int c = i >> 6, r = i & 63;
        WT[(size_t)(c0 + c) * R + r0 + r] = t[r][c];
    }
}

// ---------------- prep: V^T bf16   Vt[64bh*64 + d][1024 s]  (from bf16 qkv) --------
__global__ __launch_bounds__(256) void prep_vt(const u16* __restrict__ qkvb,
                                               u16* __restrict__ Vt) {
    __shared__ u16 ts[64][65];
    const int tid = threadIdx.x;
    const int s0 = blockIdx.x * 64;
    const int bh = blockIdx.y, b = bh >> 4, h = bh & 15;
    #pragma unroll
    for (int it = 0; it < 4; ++it) {
        int s = it * 16 + (tid >> 4);
        int d4 = (tid & 15) * 4;
        const u16* p = qkvb + (size_t)(b * 1024 + s0 + s) * 3072 + 2048 + h * 64 + d4;
        #pragma unroll
        for (int i = 0; i < 4; ++i) ts[s][d4 + i] = p[i];
    }
    __syncthreads();
    const int d = tid >> 2, si = (tid & 3) * 16;
    __align__(16) u16 buf[16];
    #pragma unroll
    for (int i = 0; i < 16; ++i) buf[i] = ts[si + i][d];
    u16* o = Vt + ((size_t)(bh * 64 + d) << 10) + s0 + si;
    *(uint4*)o       = ((uint4*)buf)[0];
    *(uint4*)(o + 8) = ((uint4*)buf)[1];
}

// ---------------- MFMA fused attention with RPE (flash-style, barrier-free) --------
// Q/K fragments read directly from bf16 qkv; y written bf16.
__global__ __launch_bounds__(256) void attn_mfma(const u16* __restrict__ qkvb,
                                                 const u16* __restrict__ Vt,
                                                 const u16* __restrict__ EKT,
                                                 const u16* __restrict__ EVT,
                                                 u16* __restrict__ yb) {
    __shared__ __align__(16) u16 S2l[4][16 * 80];
    __shared__ __align__(16) u16 Pl [4][2 * 512];
    __shared__ __align__(16) u16 Ppl[4][3 * 512];

    const int tid = threadIdx.x;
    const int w = tid >> 6, L = tid & 63;
    const int l15 = L & 15, quad = L >> 4;
    const int tile = (int)gridDim.x - 1 - (int)blockIdx.x;   // heavy tiles first
    const int t0 = tile * 64;
    const int bh = blockIdx.y, b = bh >> 4, h = bh & 15;
    const int W0 = (w >> 1) * 32;

    bf8 qn[2], qs[2];   // plain (for S2) and 0.125-scaled (for S1)
    {
        const int trow = t0 + w * 16 + l15;
        const u16* qp = qkvb + (size_t)(b * 1024 + trow) * 3072 + h * 64 + quad * 8;
        qn[0] = *(const bf8*)qp;
        qn[1] = *(const bf8*)(qp + 32);
        #pragma unroll
        for (int kc = 0; kc < 2; ++kc)
            #pragma unroll
            for (int i = 0; i < 8; ++i)
                qs[kc][i] = (short)f2b(b2f((u16)qn[kc][i]) * 0.125f);
    }

    f32x4 o[4] = {};
    float mrow[4] = {-1e30f, -1e30f, -1e30f, -1e30f};
    float lrow[4] = {0.f, 0.f, 0.f, 0.f};

    const int nch = (t0 >> 6) + 1;
    for (int c = 0; c < nch; ++c) {
        const int s0 = c << 6;
        const int diff = t0 - s0;

        // ---- S1 = (0.125*Q) @ K^T, K straight from qkv ----
        f32x4 s1[4] = {};
        {
            const u16* kbase = qkvb + (size_t)(b * 1024 + s0) * 3072 + 1024 + h * 64 + quad * 8;
            #pragma unroll
            for (int tn = 0; tn < 4; ++tn) {
                const u16* kp = kbase + (size_t)(tn * 16 + l15) * 3072;
                #pragma unroll
                for (int kc = 0; kc < 2; ++kc)
                    s1[tn] = __builtin_amdgcn_mfma_f32_16x16x32_bf16(
                        qs[kc], *(const bf8*)(kp + kc * 32), s1[tn], 0, 0, 0);
            }
        }
        // ---- S2 = Q @ EK^T over wave delta-window ----
        f32x4 s2[5] = {};
        {
            const u16* ekbase = EKT + ((size_t)(1 + diff + w * 16 + l15) << 6) + quad * 8;
            #pragma unroll
            for (int j = 0; j < 5; ++j) {
                const u16* ep = ekbase + ((size_t)(j * 16) << 6);
                #pragma unroll
                for (int kc = 0; kc < 2; ++kc)
                    s2[j] = __builtin_amdgcn_mfma_f32_16x16x32_bf16(
                        qn[kc], *(const bf8*)(ep + kc * 32), s2[j], 0, 0, 0);
            }
        }
        #pragma unroll
        for (int j = 0; j < 5; ++j)
            #pragma unroll
            for (int r = 0; r < 4; ++r)
                S2l[w][(quad * 4 + r) * 80 + j * 16 + l15] = f2b(s2[j][r]);
        #pragma unroll
        for (int i = 0; i < 3; ++i)
            ((uint4*)Ppl[w])[i * 64 + L] = make_uint4(0, 0, 0, 0);
        LDS_FENCE();

        // ---- logits + online softmax (C-layout) ----
        #pragma unroll
        for (int tn = 0; tn < 4; ++tn) {
            const int cl = tn * 16 + l15;
            #pragma unroll
            for (int r = 0; r < 4; ++r) {
                const int row = quad * 4 + r;
                float v = s1[tn][r] + b2f(S2l[w][row * 80 + (row - cl + 63)]);
                if (cl > diff + w * 16 + row) v = -1e30f;
                s1[tn][r] = v;
            }
        }
        #pragma unroll
        for (int r = 0; r < 4; ++r) {
            float mx = fmaxf(fmaxf(s1[0][r], s1[1][r]), fmaxf(s1[2][r], s1[3][r]));
            mx = fmaxf(mx, __shfl_xor(mx, 1));
            mx = fmaxf(mx, __shfl_xor(mx, 2));
            mx = fmaxf(mx, __shfl_xor(mx, 4));
            mx = fmaxf(mx, __shfl_xor(mx, 8));
            const float mnew = fmaxf(mrow[r], mx);
            const float alpha = __expf(mrow[r] - mnew);
            mrow[r] = mnew;
            float rs = 0.f;
            #pragma unroll
            for (int tn = 0; tn < 4; ++tn) {
                float p = __expf(s1[tn][r] - mnew);
                s1[tn][r] = p;
                rs += p;
            }
            rs += __shfl_xor(rs, 1); rs += __shfl_xor(rs, 2);
            rs += __shfl_xor(rs, 4); rs += __shfl_xor(rs, 8);
            lrow[r] = lrow[r] * alpha + rs;
            #pragma unroll
            for (int tn = 0; tn < 4; ++tn) o[tn][r] *= alpha;
        }
        // ---- write P and sheared P' in MFMA A-layout ----
        #pragma unroll
        for (int tn = 0; tn < 4; ++tn) {
            const int cl = tn * 16 + l15;
            #pragma unroll
            for (int r = 0; r < 4; ++r) {
                const int row = quad * 4 + r;
                const u16 pb = f2b(s1[tn][r]);
                Pl[w][((cl >> 5) << 9) + (((cl >> 3) & 3) << 7) + (row << 3) + (cl & 7)] = pb;
                const int dc = (w & 1) * 16 + row - cl + 63;
                Ppl[w][((dc >> 5) << 9) + (((dc >> 3) & 3) << 7) + (row << 3) + (dc & 7)] = pb;
            }
        }
        LDS_FENCE();

        // ---- O += P @ V ----
        {
            bf8 pa[2];
            #pragma unroll
            for (int kc = 0; kc < 2; ++kc) pa[kc] = ((const bf8*)Pl[w])[kc * 64 + L];
            const u16* vbase = Vt + ((size_t)(bh * 64 + l15) << 10) + s0 + quad * 8;
            #pragma unroll
            for (int tn = 0; tn < 4; ++tn) {
                const u16* vp = vbase + ((size_t)(tn * 16) << 10);
                #pragma unroll
                for (int kc = 0; kc < 2; ++kc)
                    o[tn] = __builtin_amdgcn_mfma_f32_16x16x32_bf16(
                        pa[kc], *(const bf8*)(vp + kc * 32), o[tn], 0, 0, 0);
            }
        }
        // ---- O += P' @ EV ----
        {
            bf8 pa[3];
            #pragma unroll
            for (int kc = 0; kc < 3; ++kc) pa[kc] = ((const bf8*)Ppl[w])[kc * 64 + L];
            const u16* evbase = EVT + (size_t)l15 * 1152 + diff + W0 + quad * 8;
            #pragma unroll
            for (int tn = 0; tn < 4; ++tn) {
                const u16* evp = evbase + (size_t)(tn * 16) * 1152;
                #pragma unroll
                for (int kc = 0; kc < 3; ++kc)
                    o[tn] = __builtin_amdgcn_mfma_f32_16x16x32_bf16(
                        pa[kc], *(const bf8*)(evp + kc * 32), o[tn], 0, 0, 0);
            }
        }
        LDS_FENCE();
    }
    #pragma unroll
    for (int tn = 0; tn < 4; ++tn) {
        const int col = h * 64 + tn * 16 + l15;
        #pragma unroll
        for (int r = 0; r < 4; ++r) {
            const int trow = t0 + w * 16 + quad * 4 + r;
            yb[(size_t)(b * 1024 + trow) * 1024 + col] = f2b(o[tn][r] / lrow[r]);
        }
    }
}

extern "C" void kernel_launch(void* const* d_in, const int* in_sizes, int n_in,
                              void* d_out, int out_size, void* d_ws, size_t ws_size,
                              hipStream_t stream) {
    const float* x      = (const float*)d_in[0];
    const float* w_attn = (const float*)d_in[1];
    const float* w_proj = (const float*)d_in[2];
    const float* embk   = (const float*)d_in[3];
    const float* embv   = (const float*)d_in[4];
    float* out = (float*)d_out;

    u16* wsb   = (u16*)d_ws;
    u16* qkvb  = wsb;                  // 4096*3072
    u16* ymidb = qkvb + 12582912;      // 4096*1024
    u16* xb    = ymidb + 4194304;      // 4096*1024
    u16* waT   = xb + 4194304;         // 3072*1024
    u16* wpT   = waT + 3145728;        // 1024*1024
    u16* Vt    = wpT + 1048576;        // 64*64*1024
    u16* EKT   = Vt + 4194304;         // 1152*64
    u16* EVT   = EKT + 73728;          // 64*1152

    prep_conv<<<dim3(4240), 256, 0, stream>>>(x, embk, embv, xb, EKT, EVT);
    transpose_conv<<<dim3(48, 16), 256, 0, stream>>>(w_attn, waT, 1024, 3072);
    transpose_conv<<<dim3(16, 16), 256, 0, stream>>>(w_proj, wpT, 1024, 1024);
    gemm_mfma<u16><<<dim3(24, 32), 256, 0, stream>>>(xb, waT, qkvb, 4096, 3072, 1024);
    prep_vt<<<dim3(16, 64), 256, 0, stream>>>(qkvb, Vt);
    attn_mfma<<<dim3(16, 64), 256, 0, stream>>>(qkvb, Vt, EKT, EVT, ymidb);
    gemm_mfma<float><<<dim3(8, 32), 256, 0, stream>>>(ymidb, wpT, out, 4096, 1024, 1024);
}

// Round 4
// 344.831 us; speedup vs baseline: 7.7679x; 1.7100x over previous
//
#include <hip/hip_runtime.h>
#include <math.h>

typedef unsigned short u16;
typedef short bf8 __attribute__((ext_vector_type(8)));      // 8 bf16 (raw bits)
typedef float f32x4 __attribute__((ext_vector_type(4)));

__device__ __forceinline__ u16 f2b(float f) {
    union { float f; unsigned u; } x; x.f = f;
    return (u16)((x.u + 0x7FFFu + ((x.u >> 16) & 1u)) >> 16);   // RTNE
}
__device__ __forceinline__ float b2f(u16 b) {
    union { unsigned u; float f; } x; x.u = ((unsigned)b) << 16;
    return x.f;
}

__device__ __forceinline__ void async16(const void* g, void* l) {
    __builtin_amdgcn_global_load_lds(
        (const __attribute__((address_space(1))) unsigned int*)g,
        (__attribute__((address_space(3))) unsigned int*)l, 16, 0, 0);
}

__device__ __forceinline__ void cstore(float* p, float v) { *p = v; }
__device__ __forceinline__ void cstore(u16* p, float v) { *p = f2b(v); }

// wave-local LDS fence
#define LDS_FENCE() do { __builtin_amdgcn_wave_barrier(); \
                         __builtin_amdgcn_s_waitcnt(0xC07F); /* lgkmcnt(0) */ \
                         __builtin_amdgcn_wave_barrier(); } while (0)

// ---------------- bf16 MFMA GEMM (m97 structure): C[M,N] = A[M,K] @ Bt[N,K]^T ------
template<typename OutT>
__global__ __launch_bounds__(256) void gemm_mfma(const u16* __restrict__ A,
                                                 const u16* __restrict__ Bt,
                                                 OutT* __restrict__ C,
                                                 int M, int N, int K) {
    __shared__ __align__(16) u16 As[128 * 32];
    __shared__ __align__(16) u16 Bs[128 * 32];
    const int tid = threadIdx.x;
    const int w = tid >> 6, L = tid & 63;
    const int l15 = L & 15, quad = L >> 4;
    const int wm = (w >> 1) * 64, wn = (w & 1) * 64;
    const int row0 = blockIdx.y * 128, col0 = blockIdx.x * 128;
    const int laneRow = L >> 2, laneCol8 = (L & 3) * 8;

    f32x4 acc[4][4] = {};

    for (int k0 = 0; k0 < K; k0 += 32) {
        #pragma unroll
        for (int i = 0; i < 2; ++i) {
            const int seg = w * 2 + i;
            const int r = seg * 16 + laneRow;
            async16(&A[(size_t)(row0 + r) * K + k0 + laneCol8], &As[seg * 512 + L * 8]);
        }
        #pragma unroll
        for (int i = 0; i < 2; ++i) {
            const int seg = w * 2 + i;
            const int r = seg * 16 + laneRow;
            async16(&Bt[(size_t)(col0 + r) * K + k0 + laneCol8], &Bs[seg * 512 + L * 8]);
        }
        __syncthreads();
        bf8 a[4], b[4];
        #pragma unroll
        for (int mt = 0; mt < 4; ++mt)
            a[mt] = *(const bf8*)&As[(wm + mt * 16 + l15) * 32 + quad * 8];
        #pragma unroll
        for (int nt = 0; nt < 4; ++nt)
            b[nt] = *(const bf8*)&Bs[(wn + nt * 16 + l15) * 32 + quad * 8];
        #pragma unroll
        for (int mt = 0; mt < 4; ++mt)
            #pragma unroll
            for (int nt = 0; nt < 4; ++nt)
                acc[mt][nt] = __builtin_amdgcn_mfma_f32_16x16x32_bf16(
                    a[mt], b[nt], acc[mt][nt], 0, 0, 0);
        __syncthreads();
    }
    #pragma unroll
    for (int mt = 0; mt < 4; ++mt)
        #pragma unroll
        for (int nt = 0; nt < 4; ++nt) {
            const int col = col0 + wn + nt * 16 + l15;
            #pragma unroll
            for (int r = 0; r < 4; ++r) {
                const int row = row0 + wm + mt * 16 + quad * 4 + r;
                cstore(&C[(size_t)row * N + col], acc[mt][nt][r]);
            }
        }
}

// ---------------- prep: x -> bf16; EKT/EVT clamped tables (bf16, widened) ----------
// EKT [1280][64]  row r = embk[clamp(r-128)]    EVT [64][1280] col c = embv[clamp(c-127)][d]
__global__ __launch_bounds__(256) void prep_conv(const float* __restrict__ x,
                                                 const float* __restrict__ embk,
                                                 const float* __restrict__ embv,
                                                 u16* __restrict__ xb,
                                                 u16* __restrict__ EKT,
                                                 u16* __restrict__ EVT) {
    int idx = blockIdx.x * 256 + threadIdx.x;
    if (idx < 1048576) {
        const float4 v = ((const float4*)x)[idx];
        ((ushort4*)xb)[idx] = make_ushort4(f2b(v.x), f2b(v.y), f2b(v.z), f2b(v.w));
    } else if (idx < 1048576 + 20480) {
        int t = idx - 1048576;
        int row = t >> 4, d4 = (t & 15) * 4;
        int delta = row - 128;
        int cl = delta < 0 ? 0 : (delta > 1023 ? 1023 : delta);
        const float* p = embk + cl * 64 + d4;
        u16* o = EKT + row * 64 + d4;
        #pragma unroll
        for (int i = 0; i < 4; ++i) o[i] = f2b(p[i]);
    } else if (idx < 1048576 + 40960) {
        int t = idx - 1048576 - 20480;
        int d = t / 320, c4 = (t - d * 320) * 4;
        u16* o = EVT + d * 1280 + c4;
        #pragma unroll
        for (int i = 0; i < 4; ++i) {
            int delta = c4 + i - 127;
            int cl = delta < 0 ? 0 : (delta > 1023 ? 1023 : delta);
            o[i] = f2b(embv[cl * 64 + d]);
        }
    }
}

// ---------------- prep: W[R][C] f32 -> WT[C][R] bf16 ----------------
__global__ __launch_bounds__(256) void transpose_conv(const float* __restrict__ W,
                                                      u16* __restrict__ WT,
                                                      int R, int Cc) {
    __shared__ u16 t[64][65];
    const int tid = threadIdx.x;
    const int c0 = blockIdx.x * 64, r0 = blockIdx.y * 64;
    for (int i = tid; i < 4096; i += 256) {
        int r = i >> 6, c = i & 63;
        t[r][c] = f2b(W[(size_t)(r0 + r) * Cc + c0 + c]);
    }
    __syncthreads();
    for (int i = tid; i < 4096; i += 256) {
        int c = i >> 6, r = i & 63;
        WT[(size_t)(c0 + c) * R + r0 + r] = t[r][c];
    }
}

// ---------------- prep: V^T bf16   Vt[64bh*64 + d][1024 s]  (from bf16 qkv) --------
__global__ __launch_bounds__(256) void prep_vt(const u16* __restrict__ qkvb,
                                               u16* __restrict__ Vt) {
    __shared__ u16 ts[64][65];
    const int tid = threadIdx.x;
    const int s0 = blockIdx.x * 64;
    const int bh = blockIdx.y, b = bh >> 4, h = bh & 15;
    #pragma unroll
    for (int it = 0; it < 4; ++it) {
        int s = it * 16 + (tid >> 4);
        int d4 = (tid & 15) * 4;
        const u16* p = qkvb + (size_t)(b * 1024 + s0 + s) * 3072 + 2048 + h * 64 + d4;
        #pragma unroll
        for (int i = 0; i < 4; ++i) ts[s][d4 + i] = p[i];
    }
    __syncthreads();
    const int d = tid >> 2, si = (tid & 3) * 16;
    __align__(16) u16 buf[16];
    #pragma unroll
    for (int i = 0; i < 16; ++i) buf[i] = ts[si + i][d];
    u16* o = Vt + ((size_t)(bh * 64 + d) << 10) + s0 + si;
    *(uint4*)o       = ((uint4*)buf)[0];
    *(uint4*)(o + 8) = ((uint4*)buf)[1];
}

// ---------------- MFMA fused attention with RPE: 128-col chunks, pair-balanced ------
// grid (8 pairs, 64 bh); block 256 = 4 waves, wave = 16 Q rows.
// Block handles Q-tiles {15-pair, pair}: exactly 9 x 128-col chunk-iterations each.
__global__ __launch_bounds__(256) void attn_mfma(const u16* __restrict__ qkvb,
                                                 const u16* __restrict__ Vt,
                                                 const u16* __restrict__ EKT,
                                                 const u16* __restrict__ EVT,
                                                 u16* __restrict__ yb) {
    __shared__ __align__(16) u16 S2l[4][16 * 148];   // stride 148 breaks quad aliasing
    __shared__ __align__(16) u16 Pl [4][4 * 512];    // P  (16x128) in MFMA A-layout
    __shared__ __align__(16) u16 Ppl[4][5 * 512];    // P' (16x160) sheared, A-layout

    const int tid = threadIdx.x;
    const int w = tid >> 6, L = tid & 63;
    const int l15 = L & 15, quad = L >> 4;
    const int pair = blockIdx.x;
    const int bh = blockIdx.y, b = bh >> 4, h = bh & 15;
    const int W0 = (w >> 1) * 32;

    #pragma unroll 1
    for (int half = 0; half < 2; ++half) {
        const int tile = half ? pair : (15 - pair);   // heavy tile first
        const int t0 = tile * 64;

        bf8 qn[2], qs[2];
        {
            const int trow = t0 + w * 16 + l15;
            const u16* qp = qkvb + (size_t)(b * 1024 + trow) * 3072 + h * 64 + quad * 8;
            qn[0] = *(const bf8*)qp;
            qn[1] = *(const bf8*)(qp + 32);
            #pragma unroll
            for (int kc = 0; kc < 2; ++kc)
                #pragma unroll
                for (int i = 0; i < 8; ++i)
                    qs[kc][i] = (short)f2b(b2f((u16)qn[kc][i]) * 0.125f);
        }

        f32x4 o[4] = {};
        float mrow[4] = {-1e30f, -1e30f, -1e30f, -1e30f};
        float lrow[4] = {0.f, 0.f, 0.f, 0.f};

        const int nch = (t0 >> 7) + 1;
        for (int c = 0; c < nch; ++c) {
            const int s0 = c << 7;
            const int diff = t0 - s0;                 // >= 0, multiple of 64

            // ---- S2 = Q @ EK^T over wave delta-window (144 wide) ----
            f32x4 s2[9] = {};
            {
                const u16* ekbase = EKT + ((size_t)(1 + diff + w * 16 + l15) << 6) + quad * 8;
                #pragma unroll
                for (int j = 0; j < 9; ++j) {
                    const u16* ep = ekbase + ((size_t)(j * 16) << 6);
                    #pragma unroll
                    for (int kc = 0; kc < 2; ++kc)
                        s2[j] = __builtin_amdgcn_mfma_f32_16x16x32_bf16(
                            qn[kc], *(const bf8*)(ep + kc * 32), s2[j], 0, 0, 0);
                }
            }
            #pragma unroll
            for (int j = 0; j < 9; ++j)
                #pragma unroll
                for (int r = 0; r < 4; ++r)
                    S2l[w][(quad * 4 + r) * 148 + j * 16 + l15] = f2b(s2[j][r]);
            #pragma unroll
            for (int i = 0; i < 5; ++i)
                ((uint4*)Ppl[w])[i * 64 + L] = make_uint4(0, 0, 0, 0);

            // ---- S1 = (0.125*Q) @ K^T, K straight from qkv ----
            f32x4 s1[8] = {};
            {
                const u16* kbase = qkvb + (size_t)(b * 1024 + s0) * 3072 + 1024 + h * 64 + quad * 8;
                #pragma unroll
                for (int tn = 0; tn < 8; ++tn) {
                    const u16* kp = kbase + (size_t)(tn * 16 + l15) * 3072;
                    #pragma unroll
                    for (int kc = 0; kc < 2; ++kc)
                        s1[tn] = __builtin_amdgcn_mfma_f32_16x16x32_bf16(
                            qs[kc], *(const bf8*)(kp + kc * 32), s1[tn], 0, 0, 0);
                }
            }
            LDS_FENCE();

            // ---- logits + causal mask (C-layout: row = quad*4+r, col = tn*16+l15) ----
            #pragma unroll
            for (int tn = 0; tn < 8; ++tn) {
                const int cl = tn * 16 + l15;
                #pragma unroll
                for (int r = 0; r < 4; ++r) {
                    const int row = quad * 4 + r;
                    float v = s1[tn][r] + b2f(S2l[w][row * 148 + (row - cl + 127)]);
                    if (cl > diff + w * 16 + row) v = -1e30f;
                    s1[tn][r] = v;
                }
            }
            // ---- online softmax, 4 rows/lane ----
            #pragma unroll
            for (int r = 0; r < 4; ++r) {
                float mx = s1[0][r];
                #pragma unroll
                for (int tn = 1; tn < 8; ++tn) mx = fmaxf(mx, s1[tn][r]);
                mx = fmaxf(mx, __shfl_xor(mx, 1));
                mx = fmaxf(mx, __shfl_xor(mx, 2));
                mx = fmaxf(mx, __shfl_xor(mx, 4));
                mx = fmaxf(mx, __shfl_xor(mx, 8));
                const float mnew = fmaxf(mrow[r], mx);
                const float alpha = __expf(mrow[r] - mnew);
                mrow[r] = mnew;
                float rs = 0.f;
                #pragma unroll
                for (int tn = 0; tn < 8; ++tn) {
                    float p = __expf(s1[tn][r] - mnew);
                    s1[tn][r] = p;
                    rs += p;
                }
                rs += __shfl_xor(rs, 1); rs += __shfl_xor(rs, 2);
                rs += __shfl_xor(rs, 4); rs += __shfl_xor(rs, 8);
                lrow[r] = lrow[r] * alpha + rs;
                #pragma unroll
                for (int tn = 0; tn < 4; ++tn) o[tn][r] *= alpha;
            }
            // ---- write P and sheared P' in MFMA A-layout ----
            #pragma unroll
            for (int tn = 0; tn < 8; ++tn) {
                const int cl = tn * 16 + l15;
                #pragma unroll
                for (int r = 0; r < 4; ++r) {
                    const int row = quad * 4 + r;
                    const u16 pb = f2b(s1[tn][r]);
                    Pl[w][((cl >> 5) << 9) + (((cl >> 3) & 3) << 7) + (row << 3) + (cl & 7)] = pb;
                    const int dc = (w & 1) * 16 + row - cl + 127;   // [0,158]
                    Ppl[w][((dc >> 5) << 9) + (((dc >> 3) & 3) << 7) + (row << 3) + (dc & 7)] = pb;
                }
            }
            LDS_FENCE();

            // ---- O += P @ V ----
            {
                bf8 pa[4];
                #pragma unroll
                for (int kc = 0; kc < 4; ++kc) pa[kc] = ((const bf8*)Pl[w])[kc * 64 + L];
                const u16* vbase = Vt + ((size_t)(bh * 64 + l15) << 10) + s0 + quad * 8;
                #pragma unroll
                for (int tn = 0; tn < 4; ++tn) {
                    const u16* vp = vbase + ((size_t)(tn * 16) << 10);
                    #pragma unroll
                    for (int kc = 0; kc < 4; ++kc)
                        o[tn] = __builtin_amdgcn_mfma_f32_16x16x32_bf16(
                            pa[kc], *(const bf8*)(vp + kc * 32), o[tn], 0, 0, 0);
                }
            }
            // ---- O += P' @ EV ----
            {
                bf8 pa[5];
                #pragma unroll
                for (int kc = 0; kc < 5; ++kc) pa[kc] = ((const bf8*)Ppl[w])[kc * 64 + L];
                const u16* evbase = EVT + (size_t)l15 * 1280 + diff + W0 + quad * 8;
                #pragma unroll
                for (int tn = 0; tn < 4; ++tn) {
                    const u16* evp = evbase + (size_t)(tn * 16) * 1280;
                    #pragma unroll
                    for (int kc = 0; kc < 5; ++kc)
                        o[tn] = __builtin_amdgcn_mfma_f32_16x16x32_bf16(
                            pa[kc], *(const bf8*)(evp + kc * 32), o[tn], 0, 0, 0);
                }
            }
            LDS_FENCE();
        }
        // ---- epilogue: O / l ----
        #pragma unroll
        for (int tn = 0; tn < 4; ++tn) {
            const int col = h * 64 + tn * 16 + l15;
            #pragma unroll
            for (int r = 0; r < 4; ++r) {
                const int trow = t0 + w * 16 + quad * 4 + r;
                yb[(size_t)(b * 1024 + trow) * 1024 + col] = f2b(o[tn][r] / lrow[r]);
            }
        }
    }
}

extern "C" void kernel_launch(void* const* d_in, const int* in_sizes, int n_in,
                              void* d_out, int out_size, void* d_ws, size_t ws_size,
                              hipStream_t stream) {
    const float* x      = (const float*)d_in[0];
    const float* w_attn = (const float*)d_in[1];
    const float* w_proj = (const float*)d_in[2];
    const float* embk   = (const float*)d_in[3];
    const float* embv   = (const float*)d_in[4];
    float* out = (float*)d_out;

    u16* wsb   = (u16*)d_ws;
    u16* qkvb  = wsb;                  // 4096*3072
    u16* ymidb = qkvb + 12582912;      // 4096*1024
    u16* xb    = ymidb + 4194304;      // 4096*1024
    u16* waT   = xb + 4194304;         // 3072*1024
    u16* wpT   = waT + 3145728;        // 1024*1024
    u16* Vt    = wpT + 1048576;        // 64*64*1024
    u16* EKT   = Vt + 4194304;         // 1280*64
    u16* EVT   = EKT + 81920;          // 64*1280

    prep_conv<<<dim3(4257), 256, 0, stream>>>(x, embk, embv, xb, EKT, EVT);
    transpose_conv<<<dim3(48, 16), 256, 0, stream>>>(w_attn, waT, 1024, 3072);
    transpose_conv<<<dim3(16, 16), 256, 0, stream>>>(w_proj, wpT, 1024, 1024);
    gemm_mfma<u16><<<dim3(24, 32), 256, 0, stream>>>(xb, waT, qkvb, 4096, 3072, 1024);
    prep_vt<<<dim3(16, 64), 256, 0, stream>>>(qkvb, Vt);
    attn_mfma<<<dim3(8, 64), 256, 0, stream>>>(qkvb, Vt, EKT, EVT, ymidb);
    gemm_mfma<float><<<dim3(8, 32), 256, 0, stream>>>(ymidb, wpT, out, 4096, 1024, 1024);
}